// Round 10
// baseline (191.808 us; speedup 1.0000x reference)
//
#include <hip/hip_runtime.h>
#include <hip/hip_bf16.h>
#include <math.h>
#include <stdint.h>

// Problem constants
#define T_ROWS 16384
#define D_DIM  4096
#define E_EXP  64
#define TOPK   8

constexpr float W_SCALE   = 64.0f;     // folded into Whi/Wlo by wprep
constexpr float INV_SCALE = 1.0f / 64.0f;

constexpr int BM     = 16;             // rows per block
constexpr int KSPLIT = 4;              // waves per block = k-quarters
constexpr int KQ     = D_DIM / KSPLIT; // 1024 k per wave
constexpr int CHUNKS = KQ / 32;        // 32 chunks of k=32
constexpr int ASLOT  = 2048;           // bytes: 16 rows x 32 f32 (one chunk tile)
constexpr int WREG   = 3 * ASLOT;      // 6144 B private region per wave
constexpr int LDS_TOT = 4 * WREG;      // 24576

typedef _Float16     f16x8  __attribute__((ext_vector_type(8)));
typedef __fp16       h16x2  __attribute__((ext_vector_type(2)));
typedef float        f32x4  __attribute__((ext_vector_type(4)));
typedef unsigned int ui32x4 __attribute__((ext_vector_type(4)));

__device__ __forceinline__ void gll16(const void* g, void* l) {
    __builtin_amdgcn_global_load_lds(
        (const __attribute__((address_space(1))) void*)g,
        (__attribute__((address_space(3))) void*)l, 16, 0, 0);
}
#define WAITV(n) asm volatile("s_waitcnt vmcnt(" #n ")" ::: "memory")
#define SB0()    __builtin_amdgcn_sched_barrier(0)

// ---------------------------------------------------------------------------
// K0: W (f32 [64][4096]) -> linear hi/lo f16 [64][4096], scaled by 64.
// ---------------------------------------------------------------------------
__global__ __launch_bounds__(256) void wprep_kernel(
    const float* __restrict__ W, _Float16* __restrict__ Whi,
    _Float16* __restrict__ Wlo)
{
    const int i = blockIdx.x * 256 + threadIdx.x;     // 32768 threads, 8 k each
    const int k = i << 3;
    const float4 w0 = *(const float4*)&W[(size_t)k];
    const float4 w1 = *(const float4*)&W[(size_t)k + 4];
    const float xs[8] = {w0.x, w0.y, w0.z, w0.w, w1.x, w1.y, w1.z, w1.w};
    f16x8 hi, lo;
    #pragma unroll
    for (int j = 0; j < 8; ++j) {
        const float x = xs[j] * W_SCALE;
        const _Float16 hh = (_Float16)x;
        hi[j] = hh;
        lo[j] = (_Float16)(x - (float)hh);
    }
    *(f16x8*)(Whi + k) = hi;
    *(f16x8*)(Wlo + k) = lo;
}

// exact split of f32 into (f16-exact hi via mantissa mask) + lo, packed cvt
__device__ __forceinline__ void cvt8(const float4 x0, const float4 x1,
                                     f16x8& hi, f16x8& lo) {
    const float xs[8] = {x0.x, x0.y, x0.z, x0.w, x1.x, x1.y, x1.z, x1.w};
    float hs[8], ls[8];
    #pragma unroll
    for (int j = 0; j < 8; ++j) {
        hs[j] = __uint_as_float(__float_as_uint(xs[j]) & 0xFFFFE000u);
        ls[j] = xs[j] - hs[j];
    }
    #pragma unroll
    for (int j = 0; j < 4; ++j) {
        const h16x2 ph = __builtin_amdgcn_cvt_pkrtz(hs[2 * j], hs[2 * j + 1]);
        const h16x2 pl = __builtin_amdgcn_cvt_pkrtz(ls[2 * j], ls[2 * j + 1]);
        hi[2 * j] = (_Float16)ph[0]; hi[2 * j + 1] = (_Float16)ph[1];
        lo[2 * j] = (_Float16)pl[0]; lo[2 * j + 1] = (_Float16)pl[1];
    }
}

// ---------------------------------------------------------------------------
// K1: barrier-free fused router. Block = 16 rows x 4 waves (k-split 4).
// Each wave: private A LDS region (3-slot, gll-staged, swizzled), asm-pinned
// B register ping-pong, per-wave counted vmcnt, SB0-fenced issue groups.
// Waves interact only at the single __syncthreads before the k-split reduce.
// ---------------------------------------------------------------------------
__global__ __launch_bounds__(256, 4) void router_main_kernel(
    const float* __restrict__ h, const _Float16* __restrict__ Whi,
    const _Float16* __restrict__ Wlo, const float* __restrict__ u,
    float* __restrict__ out)
{
    __shared__ char smraw[LDS_TOT];

    const int tid  = threadIdx.x;
    const int wv   = tid >> 6;           // k-quarter 0..3
    const int lane = tid & 63;
    const int l15  = lane & 15;
    const int kg   = lane >> 4;          // 0..3
    const int row0 = blockIdx.x * BM;
    const int qb   = wv * KQ;            // k base (floats)
    const int wvbase = wv * WREG;        // private LDS region

    // ---- A staging (2 glls/chunk): gll p, lane (kg,l15) writes LDS
    // row = p*8 + kg*2 + (l15>>3), 16B-chunk (l15&7); source pre-swizzled
    // so LDS(r,c) = G(r, c ^ (r&7)); dest is linear (base + lane*16).
    const char* gA[2];
    #pragma unroll
    for (int p = 0; p < 2; ++p) {
        const int row = p * 8 + kg * 2 + (l15 >> 3);
        gA[p] = (const char*)h + ((size_t)(row0 + row) * D_DIM + qb) * 4
                + (((l15 & 7) ^ (row & 7)) << 4);
    }

    // ---- A read offsets: row l15, chunks (2kg+q) ^ (l15&7), q=0,1 ----
    int aro[2];
    #pragma unroll
    for (int q = 0; q < 2; ++q)
        aro[q] = l15 * 128 + (((2 * kg + q) ^ (l15 & 7)) << 4);

    // ---- B bases: expert et*16+l15, k-octet kg within each 32-k chunk ----
    const char* bph0 = (const char*)Whi + ((size_t)l15 * D_DIM + qb + kg * 8) * 2;
    const char* bpl0 = bph0 + (size_t)E_EXP * D_DIM * 2;   // Wlo follows Whi

    f32x4 acc[4] = {};                   // [et]
    ui32x4 b0h[4], b0l[4], b1h[4], b1l[4];

    int aCur = 0, aNxt = ASLOT, aStg = 2 * ASLOT;

    #define STAGE_A(t, off)                                           \
        { gll16(gA[0] + (size_t)(t) * 128, smraw + wvbase + (off));   \
          gll16(gA[1] + (size_t)(t) * 128, smraw + wvbase + (off) + 1024); }

    #define LOADB(t, R)                                                        \
        { _Pragma("unroll")                                                    \
          for (int et = 0; et < 4; ++et) {                                     \
              const char* ph_ = bph0 + et * 131072 + (size_t)(t) * 64;         \
              const char* pl_ = bpl0 + et * 131072 + (size_t)(t) * 64;         \
              asm volatile("global_load_dwordx4 %0, %1, off"                   \
                           : "=v"(R##h[et]) : "v"(ph_));                       \
              asm volatile("global_load_dwordx4 %0, %1, off"                   \
                           : "=v"(R##l[et]) : "v"(pl_));                       \
          } }

    #define COMPUTE(off, R)                                                    \
        { const float4 av0 = *(const float4*)(smraw + wvbase + (off) + aro[0]);\
          const float4 av1 = *(const float4*)(smraw + wvbase + (off) + aro[1]);\
          f16x8 ah, al;                                                        \
          cvt8(av0, av1, ah, al);                                              \
          _Pragma("unroll")                                                    \
          for (int et = 0; et < 4; ++et) {                                     \
              const f16x8 bh_ = __builtin_bit_cast(f16x8, R##h[et]);           \
              const f16x8 bl_ = __builtin_bit_cast(f16x8, R##l[et]);           \
              acc[et] = __builtin_amdgcn_mfma_f32_16x16x32_f16(ah, bh_, acc[et], 0, 0, 0); \
              acc[et] = __builtin_amdgcn_mfma_f32_16x16x32_f16(ah, bl_, acc[et], 0, 0, 0); \
              acc[et] = __builtin_amdgcn_mfma_f32_16x16x32_f16(al, bh_, acc[et], 0, 0, 0); \
          } }

    #define ROT() { int t_ = aCur; aCur = aNxt; aNxt = aStg; aStg = t_; }

    // prologue: chunk groups fenced so vmcnt counting is schedule-proof
    STAGE_A(0, aCur)
    LOADB(0, b0)
    SB0();                               // chunk 0's 10 issued before chunk 1's
    STAGE_A(1, aNxt)
    LOADB(1, b1)
    SB0();
    WAITV(10);                           // chunk 0 (2 gll + 8 B) landed
    SB0();

    // main loop, no barriers: per chunk 2 gll + 8 B issued; WAITV(10) leaves
    // exactly the next chunk's 10 in flight (never drains to 0).
    for (int i = 0; i < CHUNKS - 2; i += 2) {
        STAGE_A(i + 2, aStg)
        COMPUTE(aCur, b0)                // chunk i (parity 0)
        LOADB(i + 2, b0)
        WAITV(10);
        SB0();
        ROT();

        STAGE_A(i + 3, aStg)
        COMPUTE(aCur, b1)                // chunk i+1 (parity 1)
        LOADB(i + 3, b1)
        WAITV(10);
        SB0();
        ROT();
    }
    // tail: chunks 30, 31
    COMPUTE(aCur, b0)
    WAITV(0);
    SB0();
    ROT();
    COMPUTE(aCur, b1)

    // ---- k-split partials into OWN region (private; no cross-wave hazard) ----
    #pragma unroll
    for (int et = 0; et < 4; ++et)
        #pragma unroll
        for (int r = 0; r < 4; ++r)
            *(float*)(smraw + wvbase + (kg * 4 + r) * 272 + (et * 16 + l15) * 4)
                = acc[et][r];
    __syncthreads();                     // the single cross-wave handoff

    // ---- fused epilogue: wave wv handles rows wv*4..+3; lane = expert ----
    const size_t te = (size_t)T_ROWS * E_EXP;
    #pragma unroll
    for (int rr = 0; rr < 4; ++rr) {
        const int rl = wv * 4 + rr;
        const int gr = row0 + rl;
        const size_t idx = (size_t)gr * E_EXP + lane;
        const int ro = rl * 272 + lane * 4;
        const float val = (((*(const float*)(smraw + 0 * WREG + ro)
                           + *(const float*)(smraw + 1 * WREG + ro))
                           + *(const float*)(smraw + 2 * WREG + ro))
                           + *(const float*)(smraw + 3 * WREG + ro)) * INV_SCALE;

        out[2 * te + idx] = val;                      // logits_clean

        float m = val;
        #pragma unroll
        for (int off = 32; off; off >>= 1) m = fmaxf(m, __shfl_xor(m, off));
        const float p = expf(val - m);
        float ssum = p;
        #pragma unroll
        for (int off = 32; off; off >>= 1) ssum += __shfl_xor(ssum, off);
        out[1 * te + idx] = p / ssum;                 // probs

        const float uv = u[idx];
        const float g = -logf(-logf(uv));
        const float sel = val + g;
        out[3 * te + idx] = sel;                      // logits_sel

        // top-8, ties -> lowest lane (= lowest expert, matches lax.top_k)
        float v = sel;
        bool chosen = false;
        #pragma unroll
        for (int itk = 0; itk < TOPK; ++itk) {
            float mv = v;
            #pragma unroll
            for (int off = 32; off; off >>= 1) mv = fmaxf(mv, __shfl_xor(mv, off));
            const unsigned long long b = __ballot(v == mv);
            const int sl = __ffsll((long long)b) - 1;
            if (lane == sl) { chosen = true; v = -INFINITY; }
        }
        out[idx] = chosen ? 1.0f : 0.0f;              // mask
    }
}

// ---------------------------------------------------------------------------
extern "C" void kernel_launch(void* const* d_in, const int* in_sizes, int n_in,
                              void* d_out, int out_size, void* d_ws, size_t ws_size,
                              hipStream_t stream) {
    const float* h = (const float*)d_in[0];
    const float* W = (const float*)d_in[1];
    const float* u = (const float*)d_in[2];
    float* out = (float*)d_out;

    _Float16* Whi = (_Float16*)d_ws;                       // 512 KB
    _Float16* Wlo = Whi + (size_t)E_EXP * D_DIM;           // 512 KB (contiguous)

    hipLaunchKernelGGL(wprep_kernel, dim3(E_EXP * D_DIM / 8 / 256), dim3(256),
                       0, stream, W, Whi, Wlo);
    hipLaunchKernelGGL(router_main_kernel, dim3(T_ROWS / BM), dim3(256),
                       0, stream, h, Whi, Wlo, u, out);
}

// Round 11
// 89.468 us; speedup vs baseline: 2.1439x; 2.1439x over previous
//
#include <hip/hip_runtime.h>
#include <hip/hip_bf16.h>
#include <math.h>
#include <stdint.h>

// Problem constants
#define T_ROWS 16384
#define D_DIM  4096
#define E_EXP  64
#define TOPK   8

constexpr float W_SCALE   = 64.0f;     // folded into Whi/Wlo by wprep
constexpr float INV_SCALE = 1.0f / 64.0f;

constexpr int BM   = 32;               // rows per block
constexpr int BK   = 64;               // k per step
constexpr int NIT  = D_DIM / BK;       // 64
// LDS plan (triple-buffered A and B):
constexpr int ABUF = 8192;             // 32 rows x 64 f32
constexpr int BBUF = 16384;            // [hi 8KB | lo 8KB], 64 e x 64 f16 each
constexpr int B_OFF = 3 * ABUF;        // 24576
constexpr int LDS_TOT = B_OFF + 3 * BBUF;  // 73728

typedef _Float16 f16x8 __attribute__((ext_vector_type(8)));
typedef __fp16   h16x2 __attribute__((ext_vector_type(2)));
typedef float    f32x4 __attribute__((ext_vector_type(4)));

__device__ __forceinline__ void gll16(const void* g, void* l) {
    __builtin_amdgcn_global_load_lds(
        (const __attribute__((address_space(1))) void*)g,
        (__attribute__((address_space(3))) void*)l, 16, 0, 0);
}
#define WAITV(n) asm volatile("s_waitcnt vmcnt(" #n ")" ::: "memory")
#define SB0()    __builtin_amdgcn_sched_barrier(0)

// ---------------------------------------------------------------------------
// K0: W (f32 [64][4096]) -> swizzled hi/lo f16 tiles (round-6 layout).
// Tile t (k-step) = 8KB: [e][chunk c'][8 f16], c' = s ^ (e&7) for k-octet s.
// ---------------------------------------------------------------------------
__global__ __launch_bounds__(256) void wprep_kernel(
    const float* __restrict__ W, _Float16* __restrict__ Whi,
    _Float16* __restrict__ Wlo)
{
    const int i  = blockIdx.x * 256 + threadIdx.x;
    const int e  = i >> 9;
    const int k8 = i & 511;
    const int k  = k8 << 3;
    const int t  = k >> 6;
    const int s  = (k >> 3) & 7;
    const float4 w0 = *(const float4*)&W[(size_t)e * D_DIM + k];
    const float4 w1 = *(const float4*)&W[(size_t)e * D_DIM + k + 4];
    const float xs[8] = {w0.x, w0.y, w0.z, w0.w, w1.x, w1.y, w1.z, w1.w};
    f16x8 hi, lo;
    #pragma unroll
    for (int j = 0; j < 8; ++j) {
        const float x = xs[j] * W_SCALE;
        const _Float16 hh = (_Float16)x;
        hi[j] = hh;
        lo[j] = (_Float16)(x - (float)hh);
    }
    const size_t o = (size_t)t * 4096 + e * 64 + ((s ^ (e & 7)) << 3);
    *(f16x8*)(Whi + o) = hi;
    *(f16x8*)(Wlo + o) = lo;
}

// exact split of f32 into (f16-exact hi via mantissa mask) + lo, packed cvt
__device__ __forceinline__ void cvt8(const float4 x0, const float4 x1,
                                     f16x8& hi, f16x8& lo) {
    const float xs[8] = {x0.x, x0.y, x0.z, x0.w, x1.x, x1.y, x1.z, x1.w};
    float hs[8], ls[8];
    #pragma unroll
    for (int j = 0; j < 8; ++j) {
        hs[j] = __uint_as_float(__float_as_uint(xs[j]) & 0xFFFFE000u);
        ls[j] = xs[j] - hs[j];
    }
    #pragma unroll
    for (int j = 0; j < 4; ++j) {
        const h16x2 ph = __builtin_amdgcn_cvt_pkrtz(hs[2 * j], hs[2 * j + 1]);
        const h16x2 pl = __builtin_amdgcn_cvt_pkrtz(ls[2 * j], ls[2 * j + 1]);
        hi[2 * j] = (_Float16)ph[0]; hi[2 * j + 1] = (_Float16)ph[1];
        lo[2 * j] = (_Float16)pl[0]; lo[2 * j + 1] = (_Float16)pl[1];
    }
}

// ---------------------------------------------------------------------------
// K1: fused router = round-6 pipeline + m201-style 2-barrier phase + setprio.
// 512 blocks x 256 thr (4 waves); wave (wm,we) = rows wm*16..+16 x experts
// we*32..+32. All staging via global_load_lds, counted vmcnt (never 0 in loop).
// ---------------------------------------------------------------------------
__global__ __launch_bounds__(256, 2) void router_main_kernel(
    const float* __restrict__ h, const _Float16* __restrict__ Whi,
    const _Float16* __restrict__ Wlo, const float* __restrict__ u,
    float* __restrict__ out)
{
    __shared__ union {
        char raw[LDS_TOT];
        float logits[BM][E_EXP + 4];
    } sm;
    char* smb = sm.raw;

    const int tid  = threadIdx.x;
    const int wv   = tid >> 6;
    const int lane = tid & 63;
    const int l15  = lane & 15;
    const int kg   = lane >> 4;          // 0..3
    const int wm   = wv >> 1;            // m-half
    const int we   = wv & 1;             // e-half
    const int row0 = blockIdx.x * BM;

    // ---- A staging: wave stages rows wv*8..+7; lane: row 4j+kg, LDS chunk l15.
    // Content at (row, c') = global chunk c' ^ (row&15); LDS dest linear.
    const char* gA[2]; int lA[2];
    #pragma unroll
    for (int p = 0; p < 2; ++p) {
        const int j   = wv * 2 + p;
        const int row = j * 4 + kg;
        gA[p] = (const char*)h + (size_t)(row0 + row) * (D_DIM * 4)
                + ((l15 ^ (row & 15)) << 4);
        lA[p] = j * 1024;
    }
    // ---- B staging: linear copy of pre-swizzled tiles ----
    const char* gB[4]; int lB[4];
    #pragma unroll
    for (int q = 0; q < 4; ++q) {
        const int j = wv * 4 + q;
        const _Float16* src = (j < 8) ? Whi : Wlo;
        gB[q] = (const char*)src + (size_t)(j & 7) * 1024 + lane * 16;
        lB[q] = B_OFF + j * 1024;
    }

    // ---- A ds_read offsets: read row R=wm*16+l15 (R&15=l15), chunk g^l15 ----
    int aro[2][2];                       // [kc][piece]
    #pragma unroll
    for (int kc = 0; kc < 2; ++kc)
        #pragma unroll
        for (int q2 = 0; q2 < 2; ++q2)
            aro[kc][q2] = (wm * 16 + l15) * 256
                        + (((kc * 8 + kg * 2 + q2) ^ l15) << 4);
    // ---- B ds_read offsets: expert e, octet (kc*4+kg) ^ (e&7) ----
    int bro[2][2][2];                    // [sel hi/lo][es][kc]
    #pragma unroll
    for (int sel = 0; sel < 2; ++sel)
        #pragma unroll
        for (int es = 0; es < 2; ++es)
            #pragma unroll
            for (int kc = 0; kc < 2; ++kc) {
                const int e = we * 32 + es * 16 + l15;
                bro[sel][es][kc] = B_OFF + sel * 8192 + e * 128
                                 + (((kc * 4 + kg) ^ (l15 & 7)) << 4);
            }

    f32x4 acc[2] = {};                   // [es]
    float4 av[2][2];                     // tile-i A fragments (live across barrier)
    f16x8 bhf[2][2], blf[2][2];          // tile-i B fragments

    int aCur = 0, aNxt = ABUF, aStg = 2 * ABUF;
    int bCur = 0, bNxt = BBUF, bStg = 2 * BBUF;

    #define STAGE(t, aAdd, bAdd)                                   \
        { _Pragma("unroll")                                        \
          for (int p = 0; p < 2; ++p)                              \
              gll16(gA[p] + (size_t)(t) * 256, smb + (aAdd) + lA[p]); \
          _Pragma("unroll")                                        \
          for (int q = 0; q < 4; ++q)                              \
              gll16(gB[q] + (size_t)(t) * 8192, smb + (bAdd) + lB[q]); }

    #define DSREAD(aAdd, bAdd)                                                \
        { _Pragma("unroll")                                                   \
          for (int kc = 0; kc < 2; ++kc)                                      \
              _Pragma("unroll")                                               \
              for (int q2 = 0; q2 < 2; ++q2)                                  \
                  av[kc][q2] = *(const float4*)(smb + (aAdd) + aro[kc][q2]);  \
          _Pragma("unroll")                                                   \
          for (int es = 0; es < 2; ++es)                                      \
              _Pragma("unroll")                                               \
              for (int kc = 0; kc < 2; ++kc) {                                \
                  bhf[es][kc] = *(const f16x8*)(smb + (bAdd) + bro[0][es][kc]);\
                  blf[es][kc] = *(const f16x8*)(smb + (bAdd) + bro[1][es][kc]);\
              } }

    #define MFMAS()                                                           \
        { f16x8 ah[2], al[2];                                                 \
          cvt8(av[0][0], av[0][1], ah[0], al[0]);                             \
          cvt8(av[1][0], av[1][1], ah[1], al[1]);                             \
          _Pragma("unroll")                                                   \
          for (int es = 0; es < 2; ++es)                                      \
              _Pragma("unroll")                                               \
              for (int kc = 0; kc < 2; ++kc) {                                \
                  acc[es] = __builtin_amdgcn_mfma_f32_16x16x32_f16(ah[kc], bhf[es][kc], acc[es], 0, 0, 0); \
                  acc[es] = __builtin_amdgcn_mfma_f32_16x16x32_f16(ah[kc], blf[es][kc], acc[es], 0, 0, 0); \
                  acc[es] = __builtin_amdgcn_mfma_f32_16x16x32_f16(al[kc], bhf[es][kc], acc[es], 0, 0, 0); \
              } }

    #define ROT() { int t_;                                        \
        t_ = aCur; aCur = aNxt; aNxt = aStg; aStg = t_;            \
        t_ = bCur; bCur = bNxt; bNxt = bStg; bStg = t_; }

    // prologue: tiles 0,1 staged (12 gll in flight)
    STAGE(0, aCur, bCur)
    STAGE(1, aNxt, bNxt)
    WAITV(6);                            // tile 0's 6 landed
    __builtin_amdgcn_s_barrier();

    // main loop: {ds_read(i) | stage(i+2)} -> barrier -> MFMA(i) -> vmcnt(6)
    // -> barrier. Tile i+2's 6 loads stay in flight across both barriers.
    for (int i = 0; i < NIT - 2; ++i) {
        DSREAD(aCur, bCur)
        STAGE(i + 2, aStg, bStg)
        SB0();
        __builtin_amdgcn_s_barrier();
        __builtin_amdgcn_s_setprio(1);
        MFMAS()
        __builtin_amdgcn_s_setprio(0);
        WAITV(6);                        // tile i+1 ready for next iteration
        SB0();
        __builtin_amdgcn_s_barrier();
        ROT();
    }
    // tail: tiles 62, 63 (no staging)
    DSREAD(aCur, bCur)
    __builtin_amdgcn_s_barrier();
    MFMAS()
    WAITV(0);                            // tile 63 fully landed
    SB0();
    __builtin_amdgcn_s_barrier();
    ROT();
    DSREAD(aCur, bCur)
    MFMAS()
    __builtin_amdgcn_s_barrier();        // all LDS reads done -> safe to alias

    // ---- fused epilogue ----
    #pragma unroll
    for (int es = 0; es < 2; ++es)
        #pragma unroll
        for (int r = 0; r < 4; ++r)
            sm.logits[wm * 16 + kg * 4 + r][we * 32 + es * 16 + l15]
                = acc[es][r] * INV_SCALE;
    __syncthreads();

    const size_t te = (size_t)T_ROWS * E_EXP;
    #pragma unroll
    for (int rr = 0; rr < 8; ++rr) {
        const int rl = wv * 8 + rr;
        const int gr = row0 + rl;
        const size_t idx = (size_t)gr * E_EXP + lane;
        const float val = sm.logits[rl][lane];

        out[2 * te + idx] = val;                      // logits_clean

        float m = val;
        #pragma unroll
        for (int off = 32; off; off >>= 1) m = fmaxf(m, __shfl_xor(m, off));
        const float p = expf(val - m);
        float ssum = p;
        #pragma unroll
        for (int off = 32; off; off >>= 1) ssum += __shfl_xor(ssum, off);
        out[1 * te + idx] = p / ssum;                 // probs

        const float uv = u[idx];
        const float g = -logf(-logf(uv));
        const float sel = val + g;
        out[3 * te + idx] = sel;                      // logits_sel

        // top-8, ties -> lowest lane (= lowest expert, matches lax.top_k)
        float v = sel;
        bool chosen = false;
        #pragma unroll
        for (int itk = 0; itk < TOPK; ++itk) {
            float mv = v;
            #pragma unroll
            for (int off = 32; off; off >>= 1) mv = fmaxf(mv, __shfl_xor(mv, off));
            const unsigned long long b = __ballot(v == mv);
            const int sl = __ffsll((long long)b) - 1;
            if (lane == sl) { chosen = true; v = -INFINITY; }
        }
        out[idx] = chosen ? 1.0f : 0.0f;              // mask
    }
}

// ---------------------------------------------------------------------------
extern "C" void kernel_launch(void* const* d_in, const int* in_sizes, int n_in,
                              void* d_out, int out_size, void* d_ws, size_t ws_size,
                              hipStream_t stream) {
    const float* h = (const float*)d_in[0];
    const float* W = (const float*)d_in[1];
    const float* u = (const float*)d_in[2];
    float* out = (float*)d_out;

    _Float16* Whi = (_Float16*)d_ws;                       // 512 KB (swizzled tiles)
    _Float16* Wlo = Whi + (size_t)E_EXP * D_DIM;           // 512 KB

    hipLaunchKernelGGL(wprep_kernel, dim3(E_EXP * D_DIM / 8 / 256), dim3(256),
                       0, stream, W, Whi, Wlo);
    hipLaunchKernelGGL(router_main_kernel, dim3(T_ROWS / BM), dim3(256),
                       0, stream, h, Whi, Wlo, u, out);
}

// Round 12
// 86.329 us; speedup vs baseline: 2.2218x; 1.0364x over previous
//
#include <hip/hip_runtime.h>
#include <hip/hip_bf16.h>
#include <math.h>
#include <stdint.h>

// Problem constants
#define T_ROWS 16384
#define D_DIM  4096
#define E_EXP  64
#define TOPK   8

constexpr float W_SCALE   = 64.0f;     // folded into W tiles by wprep
constexpr float INV_SCALE = 1.0f / 64.0f;

constexpr int BM   = 32;               // rows per block
constexpr int BK   = 32;               // k per step
constexpr int KHALF = D_DIM / 2;       // 2048 k per block (split-K = 2)
constexpr int NIT  = KHALF / BK;       // 64 iterations
constexpr int ABUF = 4096;             // 32 rows x 8 chunks x 16B
constexpr int BBUF = 8192;             // [hi 4KB | lo 4KB] per 32-k tile
constexpr int B_OFF = 3 * ABUF;        // 12288
constexpr int LDS_TOT = B_OFF + 3 * BBUF;  // 36864 -> 4 blocks/CU

typedef _Float16 f16x8 __attribute__((ext_vector_type(8)));
typedef __fp16   h16x2 __attribute__((ext_vector_type(2)));
typedef float    f32x4 __attribute__((ext_vector_type(4)));

__device__ __forceinline__ void gll16(const void* g, void* l) {
    __builtin_amdgcn_global_load_lds(
        (const __attribute__((address_space(1))) void*)g,
        (__attribute__((address_space(3))) void*)l, 16, 0, 0);
}
#define WAITV(n) asm volatile("s_waitcnt vmcnt(" #n ")" ::: "memory")
#define SB0()    __builtin_amdgcn_sched_barrier(0)

// ---------------------------------------------------------------------------
// K0: W (f32 [64][4096]) -> per-32k-tile packed hi/lo f16 (scaled by 64).
// Tile t (0..127) = 8KB: [hi: e*64B + c'*16B | lo: +4KB], c' = s ^ (e&3),
// s = k-octet 0..3 within the tile.
// ---------------------------------------------------------------------------
__global__ __launch_bounds__(256) void wprep_kernel(
    const float* __restrict__ W, _Float16* __restrict__ Wt)
{
    const int i  = blockIdx.x * 256 + threadIdx.x;    // 32768 threads, 8 k each
    const int e  = i >> 9;
    const int k8 = i & 511;
    const int k  = k8 << 3;
    const int t  = k >> 5;               // 32-k tile
    const int s  = (k >> 3) & 3;         // octet within tile
    const float4 w0 = *(const float4*)&W[(size_t)e * D_DIM + k];
    const float4 w1 = *(const float4*)&W[(size_t)e * D_DIM + k + 4];
    const float xs[8] = {w0.x, w0.y, w0.z, w0.w, w1.x, w1.y, w1.z, w1.w};
    f16x8 hi, lo;
    #pragma unroll
    for (int j = 0; j < 8; ++j) {
        const float x = xs[j] * W_SCALE;
        const _Float16 hh = (_Float16)x;
        hi[j] = hh;
        lo[j] = (_Float16)(x - (float)hh);
    }
    const size_t o = (size_t)t * 4096 + e * 32 + ((s ^ (e & 3)) << 3); // f16 units
    *(f16x8*)(Wt + o) = hi;
    *(f16x8*)(Wt + o + 2048) = lo;
}

// exact split of f32 into (f16-exact hi via mantissa mask) + lo, packed cvt
__device__ __forceinline__ void cvt8(const float4 x0, const float4 x1,
                                     f16x8& hi, f16x8& lo) {
    const float xs[8] = {x0.x, x0.y, x0.z, x0.w, x1.x, x1.y, x1.z, x1.w};
    float hs[8], ls[8];
    #pragma unroll
    for (int j = 0; j < 8; ++j) {
        hs[j] = __uint_as_float(__float_as_uint(xs[j]) & 0xFFFFE000u);
        ls[j] = xs[j] - hs[j];
    }
    #pragma unroll
    for (int j = 0; j < 4; ++j) {
        const h16x2 ph = __builtin_amdgcn_cvt_pkrtz(hs[2 * j], hs[2 * j + 1]);
        const h16x2 pl = __builtin_amdgcn_cvt_pkrtz(ls[2 * j], ls[2 * j + 1]);
        hi[2 * j] = (_Float16)ph[0]; hi[2 * j + 1] = (_Float16)ph[1];
        lo[2 * j] = (_Float16)pl[0]; lo[2 * j + 1] = (_Float16)pl[1];
    }
}

// ---------------------------------------------------------------------------
// K1: split-K GEMM. grid (512, 2): bx = 32-row tile, by = k-half.
// Round-11 phase-split pipeline at BK=32: per wave/iter 3 gll, WAITV(3).
// Writes raw partials to out slot (2+by)*T*E (overwritten by K2 in place).
// ---------------------------------------------------------------------------
__global__ __launch_bounds__(256, 4) void gemm_half_kernel(
    const float* __restrict__ h, const _Float16* __restrict__ Wt,
    float* __restrict__ out)
{
    __shared__ char smb[LDS_TOT];

    const int tid  = threadIdx.x;
    const int wv   = tid >> 6;
    const int lane = tid & 63;
    const int l15  = lane & 15;
    const int kg   = lane >> 4;          // 0..3
    const int wm   = wv >> 1;            // m-half
    const int we   = wv & 1;             // e-half
    const int row0 = blockIdx.x * BM;
    const int by   = blockIdx.y;         // k-half
    const int kb   = by * KHALF;         // k base (floats)

    // ---- A staging: wave stages rows wv*8..+7 (1 gll); lane = (row-sub, chunk).
    // Content at (row, c') = global chunk c' ^ (row&7); LDS dest linear.
    const int arow = wv * 8 + (lane >> 3);
    const char* gA = (const char*)h + ((size_t)(row0 + arow) * D_DIM + kb) * 4
                     + (((lane & 7) ^ (arow & 7)) << 4);
    // ---- B staging: 2 gll/wave, linear copy of pre-swizzled 8KB tile ----
    const char* gB = (const char*)Wt + (size_t)by * 64 * 8192
                     + wv * 2048 + lane * 16;
    const int lB = B_OFF + wv * 2048;

    // ---- A ds_read offsets: row R (R&7 = l15&7), chunks (2kg+q) ^ (R&7) ----
    int aro[2];
    #pragma unroll
    for (int q = 0; q < 2; ++q)
        aro[q] = (wm * 16 + l15) * 128 + (((kg * 2 + q) ^ (l15 & 7)) << 4);
    // ---- B ds_read offsets: expert e, chunk kg ^ (e&3) ----
    int bro[2][2];                       // [sel hi/lo][es]
    #pragma unroll
    for (int sel = 0; sel < 2; ++sel)
        #pragma unroll
        for (int es = 0; es < 2; ++es) {
            const int e = we * 32 + es * 16 + l15;
            bro[sel][es] = B_OFF + sel * 4096 + e * 64 + ((kg ^ (e & 3)) << 4);
        }

    f32x4 acc[2] = {};                   // [es]
    float4 av[2];
    f16x8 bhf[2], blf[2];

    int aCur = 0, aNxt = ABUF, aStg = 2 * ABUF;
    int bCur = 0, bNxt = BBUF, bStg = 2 * BBUF;

    #define STAGE(t, aAdd, bAdd)                                      \
        { gll16(gA + (size_t)(t) * 128, smb + (aAdd) + wv * 1024);    \
          gll16(gB + (size_t)(t) * 8192,        smb + (bAdd) + lB);          \
          gll16(gB + (size_t)(t) * 8192 + 1024, smb + (bAdd) + lB + 1024); }

    #define DSREAD(aAdd, bAdd)                                                \
        { av[0] = *(const float4*)(smb + (aAdd) + aro[0]);                    \
          av[1] = *(const float4*)(smb + (aAdd) + aro[1]);                    \
          _Pragma("unroll")                                                   \
          for (int es = 0; es < 2; ++es) {                                    \
              bhf[es] = *(const f16x8*)(smb + (bAdd) + bro[0][es]);           \
              blf[es] = *(const f16x8*)(smb + (bAdd) + bro[1][es]);           \
          } }

    #define MFMAS()                                                           \
        { f16x8 ah, al;                                                       \
          cvt8(av[0], av[1], ah, al);                                         \
          _Pragma("unroll")                                                   \
          for (int es = 0; es < 2; ++es) {                                    \
              acc[es] = __builtin_amdgcn_mfma_f32_16x16x32_f16(ah, bhf[es], acc[es], 0, 0, 0); \
              acc[es] = __builtin_amdgcn_mfma_f32_16x16x32_f16(ah, blf[es], acc[es], 0, 0, 0); \
              acc[es] = __builtin_amdgcn_mfma_f32_16x16x32_f16(al, bhf[es], acc[es], 0, 0, 0); \
          } }

    #define ROT() { int t_;                                        \
        t_ = aCur; aCur = aNxt; aNxt = aStg; aStg = t_;            \
        t_ = bCur; bCur = bNxt; bNxt = bStg; bStg = t_; }

    // prologue: tiles 0,1 staged; SB0 fences keep vmcnt FIFO schedule-proof
    STAGE(0, aCur, bCur)
    SB0();
    STAGE(1, aNxt, bNxt)
    SB0();
    WAITV(3);                            // tile 0's 3 landed; tile 1 in flight
    SB0();
    __builtin_amdgcn_s_barrier();

    // main loop: {ds_read(i) | stage(i+2)} -> barrier -> MFMA(i) -> vmcnt(3)
    // -> barrier. Tile i+2's 3 loads stay in flight across both barriers.
    for (int i = 0; i < NIT - 2; ++i) {
        DSREAD(aCur, bCur)
        STAGE(i + 2, aStg, bStg)
        SB0();
        __builtin_amdgcn_s_barrier();
        __builtin_amdgcn_s_setprio(1);
        MFMAS()
        __builtin_amdgcn_s_setprio(0);
        WAITV(3);                        // tile i+1 landed for next iteration
        SB0();
        __builtin_amdgcn_s_barrier();
        ROT();
    }
    // tail: tiles 62, 63 (no staging)
    DSREAD(aCur, bCur)
    __builtin_amdgcn_s_barrier();
    MFMAS()
    WAITV(0);                            // tile 63 fully landed
    SB0();
    __builtin_amdgcn_s_barrier();
    ROT();
    DSREAD(aCur, bCur)
    MFMAS()

    // ---- write raw partials to out slot (2+by): scaled by 64, summed by K2.
    // C/D: row = kg*4+r within m-tile, col = l15 within e-tile.
    float* slot = out + (size_t)(2 + by) * T_ROWS * E_EXP;
    #pragma unroll
    for (int es = 0; es < 2; ++es)
        #pragma unroll
        for (int r = 0; r < 4; ++r)
            slot[(size_t)(row0 + wm * 16 + kg * 4 + r) * E_EXP
                 + we * 32 + es * 16 + l15] = acc[es][r];
}

// ---------------------------------------------------------------------------
// K2: per-row epilogue (round-1 verified structure). One wave per row,
// lane == expert. Reads the two raw partials from slots 2,3 and overwrites
// all four outputs in place.
// ---------------------------------------------------------------------------
__global__ __launch_bounds__(256) void epilogue_kernel(
    const float* __restrict__ u, float* __restrict__ out)
{
    const int row  = blockIdx.x * 4 + (threadIdx.x >> 6);
    const int lane = threadIdx.x & 63;
    const size_t te = (size_t)T_ROWS * E_EXP;
    const size_t idx = (size_t)row * E_EXP + lane;

    const float p0 = out[2 * te + idx];
    const float p1 = out[3 * te + idx];
    const float val = (p0 + p1) * INV_SCALE;

    out[2 * te + idx] = val;             // logits_clean

    float m = val;
    #pragma unroll
    for (int off = 32; off; off >>= 1) m = fmaxf(m, __shfl_xor(m, off));
    const float p = expf(val - m);
    float ssum = p;
    #pragma unroll
    for (int off = 32; off; off >>= 1) ssum += __shfl_xor(ssum, off);
    out[1 * te + idx] = p / ssum;        // probs

    const float uv = u[idx];
    const float g = -logf(-logf(uv));
    const float sel = val + g;
    out[3 * te + idx] = sel;             // logits_sel

    // top-8, ties -> lowest lane (= lowest expert, matches lax.top_k)
    float v = sel;
    bool chosen = false;
    #pragma unroll
    for (int itk = 0; itk < TOPK; ++itk) {
        float mv = v;
        #pragma unroll
        for (int off = 32; off; off >>= 1) mv = fmaxf(mv, __shfl_xor(mv, off));
        const unsigned long long b = __ballot(v == mv);
        const int sl = __ffsll((long long)b) - 1;
        if (lane == sl) { chosen = true; v = -INFINITY; }
    }
    out[idx] = chosen ? 1.0f : 0.0f;     // mask
}

// ---------------------------------------------------------------------------
extern "C" void kernel_launch(void* const* d_in, const int* in_sizes, int n_in,
                              void* d_out, int out_size, void* d_ws, size_t ws_size,
                              hipStream_t stream) {
    const float* h = (const float*)d_in[0];
    const float* W = (const float*)d_in[1];
    const float* u = (const float*)d_in[2];
    float* out = (float*)d_out;

    _Float16* Wt = (_Float16*)d_ws;                        // 1 MB packed tiles

    hipLaunchKernelGGL(wprep_kernel, dim3(E_EXP * D_DIM / 8 / 256), dim3(256),
                       0, stream, W, Wt);
    hipLaunchKernelGGL(gemm_half_kernel, dim3(T_ROWS / BM, 2), dim3(256),
                       0, stream, h, Wt, out);
    hipLaunchKernelGGL(epilogue_kernel, dim3(T_ROWS / 4), dim3(256),
                       0, stream, u, out);
}

// Round 14
// 79.017 us; speedup vs baseline: 2.4274x; 1.0925x over previous
//
#include <hip/hip_runtime.h>
#include <hip/hip_bf16.h>
#include <math.h>
#include <stdint.h>

// Problem constants
#define T_ROWS 16384
#define D_DIM  4096
#define E_EXP  64
#define TOPK   8

constexpr float W_SCALE   = 64.0f;     // folded into W tiles by wprep
constexpr float INV_SCALE = 1.0f / 64.0f;

constexpr int BM   = 64;               // rows per block
constexpr int BK   = 32;               // k per step
constexpr int KQ   = D_DIM / 4;        // 1024 k per block (split-K = 4)
constexpr int NIT  = KQ / BK;          // 32 iterations
constexpr int ABUF = 8192;             // 64 rows x 8 chunks x 16B
constexpr int BBUF = 8192;             // [hi 4KB | lo 4KB] per 32-k tile
constexpr int B_OFF = 3 * ABUF;        // 24576 (A triple-buffered)
constexpr int LDS_TOT = B_OFF + 2 * BBUF;  // 40960 -> 4 blocks/CU

typedef _Float16 f16x8 __attribute__((ext_vector_type(8)));
typedef __fp16   h16x2 __attribute__((ext_vector_type(2)));
typedef float    f32x4 __attribute__((ext_vector_type(4)));

__device__ __forceinline__ void gll16(const void* g, void* l) {
    __builtin_amdgcn_global_load_lds(
        (const __attribute__((address_space(1))) void*)g,
        (__attribute__((address_space(3))) void*)l, 16, 0, 0);
}
#define WAITV(n) asm volatile("s_waitcnt vmcnt(" #n ")" ::: "memory")
#define SB0()    __builtin_amdgcn_sched_barrier(0)

// ---------------------------------------------------------------------------
// K0: W (f32 [64][4096]) -> per-32k-tile packed hi/lo f16 (scaled by 64).
// Tile t (0..127) = 8KB: [hi: e*64B + c'*16B | lo: +4KB], c' = s ^ (e&3).
// ---------------------------------------------------------------------------
__global__ __launch_bounds__(256) void wprep_kernel(
    const float* __restrict__ W, _Float16* __restrict__ Wt)
{
    const int i  = blockIdx.x * 256 + threadIdx.x;    // 32768 threads, 8 k each
    const int e  = i >> 9;
    const int k8 = i & 511;
    const int k  = k8 << 3;
    const int t  = k >> 5;               // 32-k tile
    const int s  = (k >> 3) & 3;         // octet within tile
    const float4 w0 = *(const float4*)&W[(size_t)e * D_DIM + k];
    const float4 w1 = *(const float4*)&W[(size_t)e * D_DIM + k + 4];
    const float xs[8] = {w0.x, w0.y, w0.z, w0.w, w1.x, w1.y, w1.z, w1.w};
    f16x8 hi, lo;
    #pragma unroll
    for (int j = 0; j < 8; ++j) {
        const float x = xs[j] * W_SCALE;
        const _Float16 hh = (_Float16)x;
        hi[j] = hh;
        lo[j] = (_Float16)(x - (float)hh);
    }
    const size_t o = (size_t)t * 4096 + e * 32 + ((s ^ (e & 3)) << 3); // f16 units
    *(f16x8*)(Wt + o) = hi;
    *(f16x8*)(Wt + o + 2048) = lo;
}

// exact split of f32 into (f16-exact hi via mantissa mask) + lo, packed cvt
__device__ __forceinline__ void cvt8(const float4 x0, const float4 x1,
                                     f16x8& hi, f16x8& lo) {
    const float xs[8] = {x0.x, x0.y, x0.z, x0.w, x1.x, x1.y, x1.z, x1.w};
    float hs[8], ls[8];
    #pragma unroll
    for (int j = 0; j < 8; ++j) {
        hs[j] = __uint_as_float(__float_as_uint(xs[j]) & 0xFFFFE000u);
        ls[j] = xs[j] - hs[j];
    }
    #pragma unroll
    for (int j = 0; j < 4; ++j) {
        const h16x2 ph = __builtin_amdgcn_cvt_pkrtz(hs[2 * j], hs[2 * j + 1]);
        const h16x2 pl = __builtin_amdgcn_cvt_pkrtz(ls[2 * j], ls[2 * j + 1]);
        hi[2 * j] = (_Float16)ph[0]; hi[2 * j + 1] = (_Float16)ph[1];
        lo[2 * j] = (_Float16)pl[0]; lo[2 * j + 1] = (_Float16)pl[1];
    }
}

// ---------------------------------------------------------------------------
// K1: split-K=4 GEMM, BM=64. grid (256, 4): bx = 64-row tile, by = k-quarter.
// Wave (wm,we): rows {wm*16..+16, 32+wm*16..+16} x experts we*32..+32;
// B fragments read from LDS once, reused for both m-frags (12 MFMA/iter).
// A triple-buffered (lookahead 2), B double-buffered (lookahead 1, L2-hot).
// Per iter per wave: 2 B-gll, SB0, 2 A-gll; WAITV(2) leaves only A(i+2).
// ---------------------------------------------------------------------------
__global__ __launch_bounds__(256, 4) void gemm_q_kernel(
    const float* __restrict__ h, const _Float16* __restrict__ Wt,
    float* __restrict__ out)
{
    __shared__ char smb[LDS_TOT];

    const int tid  = threadIdx.x;
    const int wv   = tid >> 6;
    const int lane = tid & 63;
    const int l15  = lane & 15;
    const int kg   = lane >> 4;          // 0..3
    const int wm   = wv >> 1;            // m-quarter (within each 32-row half)
    const int we   = wv & 1;             // e-half
    const int row0 = blockIdx.x * BM;
    const int q    = blockIdx.y;         // k-quarter
    const int kb   = q * KQ;

    // ---- A staging: wave stages rows wv*16..+15 via 2 glls (8 rows each).
    // Lane: row p*8 + (lane>>3), chunk slot lane&7; source chunk pre-swizzled
    // (lane&7) ^ (row&7) so LDS(r,c') = G(r, c' ^ (r&7)); dest linear.
    const char* gA[2]; int lA[2];
    #pragma unroll
    for (int p = 0; p < 2; ++p) {
        const int row = wv * 16 + p * 8 + (lane >> 3);
        gA[p] = (const char*)h + ((size_t)(row0 + row) * D_DIM + kb) * 4
                + (((lane & 7) ^ (lane >> 3)) << 4);
        lA[p] = wv * 2048 + p * 1024;
    }
    // ---- B staging: 2 glls/wave, linear copy of pre-swizzled 8KB tiles.
    // Quarter q's tiles start at tile q*32 -> byte offset q*32*8192.
    const char* gB = (const char*)Wt + (size_t)(q * 32) * 8192
                     + wv * 2048 + lane * 16;
    const int lB = wv * 2048;            // + B_OFF + par*BBUF at use

    // ---- A ds_read offsets: m-frag f -> row f*32 + wm*16 + l15 ----
    int aro[2][2];                       // [f][piece]
    #pragma unroll
    for (int f = 0; f < 2; ++f)
        #pragma unroll
        for (int qq = 0; qq < 2; ++qq)
            aro[f][qq] = (f * 32 + wm * 16 + l15) * 128
                       + (((kg * 2 + qq) ^ (l15 & 7)) << 4);
    // ---- B ds_read offsets: expert e, chunk kg ^ (e&3) ----
    int bro[2][2];                       // [sel hi/lo][es]
    #pragma unroll
    for (int sel = 0; sel < 2; ++sel)
        #pragma unroll
        for (int es = 0; es < 2; ++es) {
            const int e = we * 32 + es * 16 + l15;
            bro[sel][es] = sel * 4096 + e * 64 + ((kg ^ (e & 3)) << 4);
        }

    f32x4 acc[2][2] = {};                // [f][es]
    float4 av[2][2];                     // [f][piece]
    f16x8 bhf[2], blf[2];                // [es]

    int aCur = 0, aNxt = ABUF, aStg = 2 * ABUF;

    #define STAGE_A(t, aAdd)                                          \
        { _Pragma("unroll")                                           \
          for (int p = 0; p < 2; ++p)                                 \
              gll16(gA[p] + (size_t)(t) * 128, smb + (aAdd) + lA[p]); }
    #define STAGE_B(t, par)                                           \
        { gll16(gB + (size_t)(t) * 8192,        smb + B_OFF + (par) * BBUF + lB); \
          gll16(gB + (size_t)(t) * 8192 + 1024, smb + B_OFF + (par) * BBUF + lB + 1024); }

    #define DSREAD(aAdd, par)                                                 \
        { _Pragma("unroll")                                                   \
          for (int f = 0; f < 2; ++f) {                                       \
              av[f][0] = *(const float4*)(smb + (aAdd) + aro[f][0]);          \
              av[f][1] = *(const float4*)(smb + (aAdd) + aro[f][1]);          \
          }                                                                   \
          _Pragma("unroll")                                                   \
          for (int es = 0; es < 2; ++es) {                                    \
              bhf[es] = *(const f16x8*)(smb + B_OFF + (par) * BBUF + bro[0][es]); \
              blf[es] = *(const f16x8*)(smb + B_OFF + (par) * BBUF + bro[1][es]); \
          } }

    #define MFMAS()                                                           \
        { f16x8 ah[2], al[2];                                                 \
          cvt8(av[0][0], av[0][1], ah[0], al[0]);                             \
          cvt8(av[1][0], av[1][1], ah[1], al[1]);                             \
          _Pragma("unroll")                                                   \
          for (int f = 0; f < 2; ++f)                                         \
              _Pragma("unroll")                                               \
              for (int es = 0; es < 2; ++es) {                                \
                  acc[f][es] = __builtin_amdgcn_mfma_f32_16x16x32_f16(ah[f], bhf[es], acc[f][es], 0, 0, 0); \
                  acc[f][es] = __builtin_amdgcn_mfma_f32_16x16x32_f16(ah[f], blf[es], acc[f][es], 0, 0, 0); \
                  acc[f][es] = __builtin_amdgcn_mfma_f32_16x16x32_f16(al[f], bhf[es], acc[f][es], 0, 0, 0); \
              } }

    #define ROT() { int t_ = aCur; aCur = aNxt; aNxt = aStg; aStg = t_; }

    // prologue: FIFO [A0(2) | B0(2) | A1(2)]; WAITV(2) leaves A1, forces A0+B0.
    STAGE_A(0, aCur)
    SB0();
    STAGE_B(0, 0)
    SB0();
    STAGE_A(1, aNxt)
    SB0();
    WAITV(2);
    SB0();
    __builtin_amdgcn_s_barrier();

    // main loop. Invariant entering iter i: only A(i+1)'s 2 glls outstanding.
    // Issue B(i+1), fence, A(i+2); WAITV(2) forces A(i+1)+B(i+1), leaves A(i+2).
    for (int i = 0; i < NIT - 2; ++i) {
        DSREAD(aCur, i & 1)
        STAGE_B(i + 1, (i + 1) & 1)
        SB0();                           // pin FIFO order: B(i+1) before A(i+2)
        STAGE_A(i + 2, aStg)
        SB0();
        __builtin_amdgcn_s_barrier();
        __builtin_amdgcn_s_setprio(1);
        MFMAS()
        __builtin_amdgcn_s_setprio(0);
        WAITV(2);
        SB0();
        __builtin_amdgcn_s_barrier();
        ROT();
    }
    // tail: tiles NIT-2, NIT-1
    DSREAD(aCur, (NIT - 2) & 1)
    STAGE_B(NIT - 1, (NIT - 1) & 1)
    SB0();
    __builtin_amdgcn_s_barrier();
    MFMAS()
    WAITV(0);
    SB0();
    __builtin_amdgcn_s_barrier();
    ROT();
    DSREAD(aCur, (NIT - 1) & 1)
    MFMAS()

    // ---- write scaled partials to out slot q ----
    float* slot = out + (size_t)q * T_ROWS * E_EXP;
    #pragma unroll
    for (int f = 0; f < 2; ++f)
        #pragma unroll
        for (int es = 0; es < 2; ++es)
            #pragma unroll
            for (int r = 0; r < 4; ++r)
                slot[(size_t)(row0 + f * 32 + wm * 16 + kg * 4 + r) * E_EXP
                     + we * 32 + es * 16 + l15] = acc[f][es][r];
}

// ---------------------------------------------------------------------------
// K2: elementwise-safe epilogue. Each thread reads its 4 quarter-partials
// from the 4 out slots, then overwrites the same 4 addresses with
// mask / probs / logits_clean / logits_sel. One wave per row, lane = expert.
// ---------------------------------------------------------------------------
__global__ __launch_bounds__(256) void epilogue_kernel(
    const float* __restrict__ u, float* __restrict__ out)
{
    const int row  = blockIdx.x * 4 + (threadIdx.x >> 6);
    const int lane = threadIdx.x & 63;
    const size_t te = (size_t)T_ROWS * E_EXP;
    const size_t idx = (size_t)row * E_EXP + lane;

    const float p0 = out[0 * te + idx];
    const float p1 = out[1 * te + idx];
    const float p2 = out[2 * te + idx];
    const float p3 = out[3 * te + idx];
    const float val = (((p0 + p1) + p2) + p3) * INV_SCALE;

    out[2 * te + idx] = val;             // logits_clean

    float m = val;
    #pragma unroll
    for (int off = 32; off; off >>= 1) m = fmaxf(m, __shfl_xor(m, off));
    const float p = expf(val - m);
    float ssum = p;
    #pragma unroll
    for (int off = 32; off; off >>= 1) ssum += __shfl_xor(ssum, off);
    out[1 * te + idx] = p / ssum;        // probs

    const float uv = u[idx];
    const float g = -logf(-logf(uv));
    const float sel = val + g;
    out[3 * te + idx] = sel;             // logits_sel

    // top-8, ties -> lowest lane (= lowest expert, matches lax.top_k)
    float v = sel;
    bool chosen = false;
    #pragma unroll
    for (int itk = 0; itk < TOPK; ++itk) {
        float mv = v;
        #pragma unroll
        for (int off = 32; off; off >>= 1) mv = fmaxf(mv, __shfl_xor(mv, off));
        const unsigned long long b = __ballot(v == mv);
        const int sl = __ffsll((long long)b) - 1;
        if (lane == sl) { chosen = true; v = -INFINITY; }
    }
    out[idx] = chosen ? 1.0f : 0.0f;     // mask
}

// ---------------------------------------------------------------------------
extern "C" void kernel_launch(void* const* d_in, const int* in_sizes, int n_in,
                              void* d_out, int out_size, void* d_ws, size_t ws_size,
                              hipStream_t stream) {
    const float* h = (const float*)d_in[0];
    const float* W = (const float*)d_in[1];
    const float* u = (const float*)d_in[2];
    float* out = (float*)d_out;

    _Float16* Wt = (_Float16*)d_ws;                        // 1 MB packed tiles

    hipLaunchKernelGGL(wprep_kernel, dim3(E_EXP * D_DIM / 8 / 256), dim3(256),
                       0, stream, W, Wt);
    hipLaunchKernelGGL(gemm_q_kernel, dim3(T_ROWS / BM, 4), dim3(256),
                       0, stream, h, Wt, out);
    hipLaunchKernelGGL(epilogue_kernel, dim3(T_ROWS / 4), dim3(256),
                       0, stream, u, out);
}

// Round 15
// 78.071 us; speedup vs baseline: 2.4568x; 1.0121x over previous
//
#include <hip/hip_runtime.h>
#include <hip/hip_bf16.h>
#include <math.h>
#include <stdint.h>

// Problem constants
#define T_ROWS 16384
#define D_DIM  4096
#define E_EXP  64
#define TOPK   8

constexpr float W_SCALE   = 64.0f;     // folded into W tiles by wprep
constexpr float INV_SCALE = 1.0f / 64.0f;

constexpr int BM   = 64;               // rows per block
constexpr int BK   = 32;               // k per step
constexpr int KQ   = D_DIM / 4;        // 1024 k per block (split-K = 4)
constexpr int NIT  = KQ / BK;          // 32 iterations
constexpr int ABUF = 8192;             // 64 rows x 8 chunks x 16B
constexpr int BBUF = 8192;             // [hi 4KB | lo 4KB] per 32-k tile
constexpr int B_OFF = 3 * ABUF;        // 24576 (A triple-buffered)
constexpr int LDS_TOT = B_OFF + 2 * BBUF;  // 40960 -> 4 blocks/CU

typedef _Float16 f16x8 __attribute__((ext_vector_type(8)));
typedef __fp16   h16x2 __attribute__((ext_vector_type(2)));
typedef float    f32x4 __attribute__((ext_vector_type(4)));

__device__ __forceinline__ void gll16(const void* g, void* l) {
    __builtin_amdgcn_global_load_lds(
        (const __attribute__((address_space(1))) void*)g,
        (__attribute__((address_space(3))) void*)l, 16, 0, 0);
}
#define WAITV(n) asm volatile("s_waitcnt vmcnt(" #n ")" ::: "memory")
#define SB0()    __builtin_amdgcn_sched_barrier(0)

// ---------------------------------------------------------------------------
// K0: W (f32 [64][4096]) -> per-32k-tile packed hi/lo f16 (scaled by 64).
// Tile t (0..127) = 8KB: [hi: e*64B + c'*16B | lo: +4KB], c' = s ^ (e&3).
// ---------------------------------------------------------------------------
__global__ __launch_bounds__(256) void wprep_kernel(
    const float* __restrict__ W, _Float16* __restrict__ Wt)
{
    const int i  = blockIdx.x * 256 + threadIdx.x;    // 32768 threads, 8 k each
    const int e  = i >> 9;
    const int k8 = i & 511;
    const int k  = k8 << 3;
    const int t  = k >> 5;               // 32-k tile
    const int s  = (k >> 3) & 3;         // octet within tile
    const float4 w0 = *(const float4*)&W[(size_t)e * D_DIM + k];
    const float4 w1 = *(const float4*)&W[(size_t)e * D_DIM + k + 4];
    const float xs[8] = {w0.x, w0.y, w0.z, w0.w, w1.x, w1.y, w1.z, w1.w};
    f16x8 hi, lo;
    #pragma unroll
    for (int j = 0; j < 8; ++j) {
        const float x = xs[j] * W_SCALE;
        const _Float16 hh = (_Float16)x;
        hi[j] = hh;
        lo[j] = (_Float16)(x - (float)hh);
    }
    const size_t o = (size_t)t * 4096 + e * 32 + ((s ^ (e & 3)) << 3); // f16 units
    *(f16x8*)(Wt + o) = hi;
    *(f16x8*)(Wt + o + 2048) = lo;
}

// exact split of f32 into (f16-exact hi via mantissa mask) + lo, packed cvt
__device__ __forceinline__ void cvt8(const float4 x0, const float4 x1,
                                     f16x8& hi, f16x8& lo) {
    const float xs[8] = {x0.x, x0.y, x0.z, x0.w, x1.x, x1.y, x1.z, x1.w};
    float hs[8], ls[8];
    #pragma unroll
    for (int j = 0; j < 8; ++j) {
        hs[j] = __uint_as_float(__float_as_uint(xs[j]) & 0xFFFFE000u);
        ls[j] = xs[j] - hs[j];
    }
    #pragma unroll
    for (int j = 0; j < 4; ++j) {
        const h16x2 ph = __builtin_amdgcn_cvt_pkrtz(hs[2 * j], hs[2 * j + 1]);
        const h16x2 pl = __builtin_amdgcn_cvt_pkrtz(ls[2 * j], ls[2 * j + 1]);
        hi[2 * j] = (_Float16)ph[0]; hi[2 * j + 1] = (_Float16)ph[1];
        lo[2 * j] = (_Float16)pl[0]; lo[2 * j + 1] = (_Float16)pl[1];
    }
}

// ---------------------------------------------------------------------------
// K1: split-K=4 GEMM, BM=64, single barrier per iteration.
// grid (256, 4): bx = 64-row tile, by = k-quarter.
// Wave (wm,we): rows {wm*16..+16, 32+wm*16..+16} x experts we*32..+32;
// B frags read once, reused by both m-frags (12 MFMA/iter).
// Hazard audit for 1 barrier/iter:
//   RAW tile i+1: every wave's WAITV(2) (forces A(i+1)+B(i+1)) + end barrier.
//   WAR aStg (written iter i, last ds_read at iter i-1): end barrier of i-1
//     precedes the gll issue (a gll write cannot land before issue).
// ---------------------------------------------------------------------------
__global__ __launch_bounds__(256, 4) void gemm_q_kernel(
    const float* __restrict__ h, const _Float16* __restrict__ Wt,
    float* __restrict__ out)
{
    __shared__ char smb[LDS_TOT];

    const int tid  = threadIdx.x;
    const int wv   = tid >> 6;
    const int lane = tid & 63;
    const int l15  = lane & 15;
    const int kg   = lane >> 4;          // 0..3
    const int wm   = wv >> 1;            // m-quarter (within each 32-row half)
    const int we   = wv & 1;             // e-half
    const int row0 = blockIdx.x * BM;
    const int q    = blockIdx.y;         // k-quarter
    const int kb   = q * KQ;

    // ---- A staging: wave stages rows wv*16..+15 via 2 glls (8 rows each).
    // Lane: row p*8 + (lane>>3), chunk slot lane&7; source chunk pre-swizzled
    // (lane&7) ^ (row&7) so LDS(r,c') = G(r, c' ^ (r&7)); dest linear.
    const char* gA[2]; int lA[2];
    #pragma unroll
    for (int p = 0; p < 2; ++p) {
        const int row = wv * 16 + p * 8 + (lane >> 3);
        gA[p] = (const char*)h + ((size_t)(row0 + row) * D_DIM + kb) * 4
                + (((lane & 7) ^ (lane >> 3)) << 4);
        lA[p] = wv * 2048 + p * 1024;
    }
    // ---- B staging: 2 glls/wave, linear copy of pre-swizzled 8KB tiles.
    // Quarter q's tiles start at tile q*32 -> byte offset q*32*8192.
    const char* gB = (const char*)Wt + (size_t)(q * 32) * 8192
                     + wv * 2048 + lane * 16;
    const int lB = wv * 2048;            // + B_OFF + par*BBUF at use

    // ---- A ds_read offsets: m-frag f -> row f*32 + wm*16 + l15 ----
    int aro[2][2];                       // [f][piece]
    #pragma unroll
    for (int f = 0; f < 2; ++f)
        #pragma unroll
        for (int qq = 0; qq < 2; ++qq)
            aro[f][qq] = (f * 32 + wm * 16 + l15) * 128
                       + (((kg * 2 + qq) ^ (l15 & 7)) << 4);
    // ---- B ds_read offsets: expert e, chunk kg ^ (e&3) ----
    int bro[2][2];                       // [sel hi/lo][es]
    #pragma unroll
    for (int sel = 0; sel < 2; ++sel)
        #pragma unroll
        for (int es = 0; es < 2; ++es) {
            const int e = we * 32 + es * 16 + l15;
            bro[sel][es] = sel * 4096 + e * 64 + ((kg ^ (e & 3)) << 4);
        }

    f32x4 acc[2][2] = {};                // [f][es]
    float4 av[2][2];                     // [f][piece]
    f16x8 bhf[2], blf[2];                // [es]

    int aCur = 0, aNxt = ABUF, aStg = 2 * ABUF;

    #define STAGE_A(t, aAdd)                                          \
        { _Pragma("unroll")                                           \
          for (int p = 0; p < 2; ++p)                                 \
              gll16(gA[p] + (size_t)(t) * 128, smb + (aAdd) + lA[p]); }
    #define STAGE_B(t, par)                                           \
        { gll16(gB + (size_t)(t) * 8192,        smb + B_OFF + (par) * BBUF + lB); \
          gll16(gB + (size_t)(t) * 8192 + 1024, smb + B_OFF + (par) * BBUF + lB + 1024); }

    #define DSREAD(aAdd, par)                                                 \
        { _Pragma("unroll")                                                   \
          for (int f = 0; f < 2; ++f) {                                       \
              av[f][0] = *(const float4*)(smb + (aAdd) + aro[f][0]);          \
              av[f][1] = *(const float4*)(smb + (aAdd) + aro[f][1]);          \
          }                                                                   \
          _Pragma("unroll")                                                   \
          for (int es = 0; es < 2; ++es) {                                    \
              bhf[es] = *(const f16x8*)(smb + B_OFF + (par) * BBUF + bro[0][es]); \
              blf[es] = *(const f16x8*)(smb + B_OFF + (par) * BBUF + bro[1][es]); \
          } }

    #define MFMAS()                                                           \
        { f16x8 ah[2], al[2];                                                 \
          cvt8(av[0][0], av[0][1], ah[0], al[0]);                             \
          cvt8(av[1][0], av[1][1], ah[1], al[1]);                             \
          _Pragma("unroll")                                                   \
          for (int f = 0; f < 2; ++f)                                         \
              _Pragma("unroll")                                               \
              for (int es = 0; es < 2; ++es) {                                \
                  acc[f][es] = __builtin_amdgcn_mfma_f32_16x16x32_f16(ah[f], bhf[es], acc[f][es], 0, 0, 0); \
                  acc[f][es] = __builtin_amdgcn_mfma_f32_16x16x32_f16(ah[f], blf[es], acc[f][es], 0, 0, 0); \
                  acc[f][es] = __builtin_amdgcn_mfma_f32_16x16x32_f16(al[f], bhf[es], acc[f][es], 0, 0, 0); \
              } }

    #define ROT() { int t_ = aCur; aCur = aNxt; aNxt = aStg; aStg = t_; }

    // prologue: FIFO [A0(2) | B0(2) | A1(2)]; WAITV(2) leaves A1, forces A0+B0.
    STAGE_A(0, aCur)
    SB0();
    STAGE_B(0, 0)
    SB0();
    STAGE_A(1, aNxt)
    SB0();
    WAITV(2);
    SB0();
    __builtin_amdgcn_s_barrier();

    // main loop: ONE barrier per iteration.
    // Invariant entering iter i: only A(i+1)'s 2 glls outstanding.
    // Issue B(i+1), fence, A(i+2); MFMA(i); WAITV(2) forces A(i+1)+B(i+1),
    // leaves A(i+2) in flight across the barrier.
    for (int i = 0; i < NIT - 2; ++i) {
        DSREAD(aCur, i & 1)
        STAGE_B(i + 1, (i + 1) & 1)
        SB0();                           // pin FIFO order: B(i+1) before A(i+2)
        STAGE_A(i + 2, aStg)
        SB0();
        __builtin_amdgcn_s_setprio(1);
        MFMAS()
        __builtin_amdgcn_s_setprio(0);
        WAITV(2);
        SB0();
        __builtin_amdgcn_s_barrier();
        ROT();
    }
    // tail: tiles NIT-2, NIT-1
    DSREAD(aCur, (NIT - 2) & 1)
    STAGE_B(NIT - 1, (NIT - 1) & 1)
    SB0();
    MFMAS()
    WAITV(0);
    SB0();
    __builtin_amdgcn_s_barrier();
    ROT();
    DSREAD(aCur, (NIT - 1) & 1)
    MFMAS()

    // ---- write scaled partials to out slot q ----
    float* slot = out + (size_t)q * T_ROWS * E_EXP;
    #pragma unroll
    for (int f = 0; f < 2; ++f)
        #pragma unroll
        for (int es = 0; es < 2; ++es)
            #pragma unroll
            for (int r = 0; r < 4; ++r)
                slot[(size_t)(row0 + f * 32 + wm * 16 + kg * 4 + r) * E_EXP
                     + we * 32 + es * 16 + l15] = acc[f][es][r];
}

// ---------------------------------------------------------------------------
// K2: elementwise-safe epilogue. Each thread reads its 4 quarter-partials
// from the 4 out slots, then overwrites the same 4 addresses with
// mask / probs / logits_clean / logits_sel. One wave per row, lane = expert.
// ---------------------------------------------------------------------------
__global__ __launch_bounds__(256) void epilogue_kernel(
    const float* __restrict__ u, float* __restrict__ out)
{
    const int row  = blockIdx.x * 4 + (threadIdx.x >> 6);
    const int lane = threadIdx.x & 63;
    const size_t te = (size_t)T_ROWS * E_EXP;
    const size_t idx = (size_t)row * E_EXP + lane;

    const float p0 = out[0 * te + idx];
    const float p1 = out[1 * te + idx];
    const float p2 = out[2 * te + idx];
    const float p3 = out[3 * te + idx];
    const float val = (((p0 + p1) + p2) + p3) * INV_SCALE;

    out[2 * te + idx] = val;             // logits_clean

    float m = val;
    #pragma unroll
    for (int off = 32; off; off >>= 1) m = fmaxf(m, __shfl_xor(m, off));
    const float p = expf(val - m);
    float ssum = p;
    #pragma unroll
    for (int off = 32; off; off >>= 1) ssum += __shfl_xor(ssum, off);
    out[1 * te + idx] = p / ssum;        // probs

    const float uv = u[idx];
    const float g = -logf(-logf(uv));
    const float sel = val + g;
    out[3 * te + idx] = sel;             // logits_sel

    // top-8, ties -> lowest lane (= lowest expert, matches lax.top_k)
    float v = sel;
    bool chosen = false;
    #pragma unroll
    for (int itk = 0; itk < TOPK; ++itk) {
        float mv = v;
        #pragma unroll
        for (int off = 32; off; off >>= 1) mv = fmaxf(mv, __shfl_xor(mv, off));
        const unsigned long long b = __ballot(v == mv);
        const int sl = __ffsll((long long)b) - 1;
        if (lane == sl) { chosen = true; v = -INFINITY; }
    }
    out[idx] = chosen ? 1.0f : 0.0f;     // mask
}

// ---------------------------------------------------------------------------
extern "C" void kernel_launch(void* const* d_in, const int* in_sizes, int n_in,
                              void* d_out, int out_size, void* d_ws, size_t ws_size,
                              hipStream_t stream) {
    const float* h = (const float*)d_in[0];
    const float* W = (const float*)d_in[1];
    const float* u = (const float*)d_in[2];
    float* out = (float*)d_out;

    _Float16* Wt = (_Float16*)d_ws;                        // 1 MB packed tiles

    hipLaunchKernelGGL(wprep_kernel, dim3(E_EXP * D_DIM / 8 / 256), dim3(256),
                       0, stream, W, Wt);
    hipLaunchKernelGGL(gemm_q_kernel, dim3(T_ROWS / BM, 4), dim3(256),
                       0, stream, h, Wt, out);
    hipLaunchKernelGGL(epilogue_kernel, dim3(T_ROWS / 4), dim3(256),
                       0, stream, u, out);
}